// Round 11
// baseline (40.474 us; speedup 1.0000x reference)
//
#include <hip/hip_runtime.h>
#include <hip/hip_fp16.h>

// AliasFreeActivation, round 11: f16 LDS storage (half the bytes, half the
// footprint), f32 packed math. x (2,256,84,84) f32 -> up x4 (24t) -> lrelu ->
// down x2 (12t) -> crop 10 -> out (2,256,148,148) f32.
//
// Band b (10/plane): out rows i0..i0+15, i0=min(16b,132) (band 9 overlaps 8;
// duplicate stores bitwise-identical). z cols 15..320 -> local 0..305.
// Input rows IR0=i0/2+1..+15 all in-bounds.
//
// LDS layout: row r = 156 dwords, each dword = __half2 holding col pair.
// Per 8-col block B (dwords 4B..4B+3): dword 4B+c = (col 8B+c, col 8B+4+c).
//   DW(c) = ((c>>3)<<2)+(c&3), HF(c) = (c>>2)&1.
// P1 packs its (a,b) v2 results straight into this layout (uint4 store).
// P2: thread pc handles dword pc's two columns; 12 row reads (stride-1 across
// lanes = conflict-free), f32 v2 math (26 z steps, 8 accs), f16 tv writeback.
// P3: 14-dword window, unpack, U[t]=(W[t],W[t+8]), packed down-h, f32 stores.

typedef float v2 __attribute__((ext_vector_type(2)));

constexpr int IN_HW  = 84;
constexpr int OUT_HW = 148;
constexpr int STRH   = 156;               // dword stride per row (2 cols/dword)
constexpr int NIR    = 16;                // uph rows per band
constexpr int LDS_U  = NIR * STRH + 8;    // 2504 dw = 10016 B
constexpr float SLOPE = 0.2f;

__device__ __forceinline__ float rfl(float v) {
    return __uint_as_float(__builtin_amdgcn_readfirstlane(__float_as_uint(v)));
}
__device__ __forceinline__ unsigned pk16(v2 a) {
    __half2 h = __float22half2_rn(make_float2(a.x, a.y));   // RTE both halves
    return *(unsigned*)&h;
}
__device__ __forceinline__ v2 up16(unsigned u) {
    __half2 h = *(__half2*)&u;
    float2 f = __half22float2(h);
    return (v2){f.x, f.y};
}

__global__ __launch_bounds__(320, 6) void afa_band(
    const float* __restrict__ x, const float* __restrict__ ku,
    const float* __restrict__ kd, float* __restrict__ out)
{
    __shared__ unsigned sbuf16[LDS_U];
    const int lt   = threadIdx.x;
    const int band = blockIdx.x;                 // 0..9
    const int pz   = blockIdx.y;                 // 0..511
    const int i0   = (band == 9) ? 132 : 16 * band;
    const int IR0  = (i0 >> 1) + 1;

    float fu[24], fd[12];
#pragma unroll
    for (int i = 0; i < 24; ++i) fu[i] = rfl(ku[i]);
#pragma unroll
    for (int i = 0; i < 12; ++i) fd[i] = rfl(kd[i]);

    const float* xin = x + (size_t)pz * (IN_HW * IN_HW);
    float* o = out + (size_t)pz * (OUT_HW * OUT_HW);

    // ---- P1: horizontal up-conv, packed (a,b) v2 pairs -> f16 dword store ----
    // task (r,g): window w0..w7 = x[IR0+r][2g+1 .. 2g+8]; V[t]=(w[t],w[t+1]).
#pragma unroll
    for (int kk = 0; kk < 2; ++kk) {
        int e = lt + 320 * kk;
        if (e < NIR * 39) {
            int r = e / 39, g = e - r * 39;
            const float* xr = xin + (IR0 + r) * IN_HW + 2 * g;
            float2 p0 = *(const float2*)(xr);
            float2 p1 = *(const float2*)(xr + 2);
            float2 p2 = *(const float2*)(xr + 4);
            float2 p3 = *(const float2*)(xr + 6);
            float2 p4 = *(const float2*)(xr + ((g == 38) ? 6 : 8)); // avoid OOB
            v2 V0 = {p0.y, p1.x};
            v2 V1 = {p1.x, p1.y};
            v2 V2 = {p1.y, p2.x};
            v2 V3 = {p2.x, p2.y};
            v2 V4 = {p2.y, p3.x};
            v2 V5 = {p3.x, p3.y};
            v2 V6 = {p3.y, p4.x};   // V6.y garbage only feeds unread tail cols
            v2 AB0 = V5*fu[1] + V4*fu[5] + V3*fu[9]  + V2*fu[13] + V1*fu[17] + V0*fu[21];
            v2 AB1 = V5*fu[2] + V4*fu[6] + V3*fu[10] + V2*fu[14] + V1*fu[18] + V0*fu[22];
            v2 AB2 = V5*fu[3] + V4*fu[7] + V3*fu[11] + V2*fu[15] + V1*fu[19] + V0*fu[23];
            v2 AB3 = V6*fu[0] + V5*fu[4] + V4*fu[8]  + V3*fu[12] + V2*fu[16] + V1*fu[20];
            uint4 pk;
            pk.x = pk16(AB0); pk.y = pk16(AB1); pk.z = pk16(AB2); pk.w = pk16(AB3);
            *(uint4*)(sbuf16 + r * STRH + 4 * g) = pk;
        }
    }
    __syncthreads();

    // ---- P2: half-band per-dword up-v + lrelu + down-v, f32 v2 math ----
    // group A (lt<154): out rows 0..7, colv rows 0..11;
    // group B:          out rows 8..15, colv rows 4..15.
    {
        int g  = (lt >= 154);
        int pc = lt - 154 * g;
        if (pc > 153) pc = 153;                  // dup tail, same-value writes
        const unsigned* up = sbuf16 + (4 * g) * STRH + pc;
        v2 colv[12];
#pragma unroll
        for (int r = 0; r < 12; ++r) colv[r] = up16(up[r * STRH]);
        v2 zv[26];
#pragma unroll
        for (int t = 0; t < 26; ++t) {
            const int n  = (t + 1) >> 2;
            const int ph = (t + 1) & 3;
            v2 z = colv[n+5] * fu[ph];
            z += colv[n+4] * fu[ph+4];
            z += colv[n+3] * fu[ph+8];
            z += colv[n+2] * fu[ph+12];
            z += colv[n+1] * fu[ph+16];
            z += colv[n]   * fu[ph+20];
            zv[t] = __builtin_elementwise_max(z, z * SLOPE);   // lrelu
        }
        v2 acc[8];
#pragma unroll
        for (int i = 0; i < 8; ++i) {
            v2 a = zv[2*i] * fd[11];
#pragma unroll
            for (int j = 1; j < 12; ++j)
                a += zv[2*i + j] * fd[11 - j];
            acc[i] = a;
        }
        __syncthreads();                         // cross-group uph reads done
        unsigned* tvc = sbuf16 + (8 * g) * STRH + pc;
#pragma unroll
        for (int i = 0; i < 8; ++i)
            tvc[i * STRH] = pk16(acc[i]);
    }
    __syncthreads();

    // ---- P3: horizontal down-conv + store, packed out pairs (m, m+4) ----
    if (lt < NIR * 19) {
        int i = lt / 19, g8 = lt - i * 19;
        const unsigned* base = sbuf16 + i * STRH + 8 * g8;
        uint4 da = *(const uint4*)(base);
        uint4 db = *(const uint4*)(base + 4);
        uint4 dc = *(const uint4*)(base + 8);
        uint2 dd = *(const uint2*)(base + 12);
        v2 F[14];
        F[0]=up16(da.x); F[1]=up16(da.y); F[2]=up16(da.z); F[3]=up16(da.w);
        F[4]=up16(db.x); F[5]=up16(db.y); F[6]=up16(db.z); F[7]=up16(db.w);
        F[8]=up16(dc.x); F[9]=up16(dc.y); F[10]=up16(dc.z); F[11]=up16(dc.w);
        F[12]=up16(dd.x); F[13]=up16(dd.y);
        float W[26];
#pragma unroll
        for (int c = 0; c < 26; ++c) {
            const int D = ((c >> 3) << 2) + (c & 3);
            W[c] = ((c >> 2) & 1) ? F[D].y : F[D].x;
        }
        v2 U[18];                                // U[t] = (col t, col t+8)
#pragma unroll
        for (int t = 0; t < 18; ++t)
            U[t] = (v2){ W[t], W[t + 8] };
        v2 q[4];
#pragma unroll
        for (int m = 0; m < 4; ++m) {
            v2 a = U[2*m + 11] * fd[0];
#pragma unroll
            for (int u = 1; u < 12; ++u)
                a += U[2*m + 11 - u] * fd[u];
            q[m] = a;
        }
        float* orow = o + (size_t)(i0 + i) * OUT_HW + 8 * g8;
        *(float4*)(orow) = make_float4(q[0].x, q[1].x, q[2].x, q[3].x);
        if (g8 < 18)
            *(float4*)(orow + 4) = make_float4(q[0].y, q[1].y, q[2].y, q[3].y);
    }
}

extern "C" void kernel_launch(void* const* d_in, const int* in_sizes, int n_in,
                              void* d_out, int out_size, void* d_ws, size_t ws_size,
                              hipStream_t stream) {
    const float* x  = (const float*)d_in[0];
    const float* ku = (const float*)d_in[1];
    const float* kd = (const float*)d_in[2];
    float* out = (float*)d_out;
    dim3 grid(10, 512);
    afa_band<<<grid, dim3(320), 0, stream>>>(x, ku, kd, out);
}